// Round 18
// baseline (240.162 us; speedup 1.0000x reference)
//
#include <hip/hip_runtime.h>
#include <hip/hip_fp16.h>

#define N_NODES 100000
#define N_EDGES 1200000
#define N_GRAPHS 512
#define F 60
#define NPW 8      // nodes per wave in k_layer == group size
#define CAP 48     // padded CSR slots per node (P(deg>=48)*N ~ 3e-10; held r2-r17)
#define GSTRIDE 384 // CAP * 8 entries per group
#define NBKT 782   // node buckets of 128 (ceil(100000/128); last bucket has 32 nodes)
#define EPB 4096   // edges per chunk
#define CPX 37     // chunks per XCD group
#define NCH 296    // chunks total (8 * 37; NCH*EPB >= E)
#define BKT_CAP 2048 // per-bucket entry capacity (mean 1534, sigma 39 -> +13 sigma)
#define NDEG 49    // degree bins 0..48
#define WSC 3.0518509e-05f   // 1/32767: 15-bit fixed-point weight decode

// ---------------- pass A1: per-chunk histogram over dst buckets (LDS atomics only) ----
__global__ void __launch_bounds__(256) k_hist(const int* __restrict__ dst,
                                              int* __restrict__ histM, int E) {
    __shared__ int h[NBKT];
    int c = (blockIdx.x & 7) * CPX + (blockIdx.x >> 3);   // XCD-grouped chunk id
    for (int i = threadIdx.x; i < NBKT; i += 256) h[i] = 0;
    __syncthreads();
    int b0 = c * EPB;
    for (int i = threadIdx.x; i < EPB; i += 256) {
        int e = b0 + i;
        if (e < E) atomicAdd(&h[dst[e] >> 7], 1);
    }
    __syncthreads();
    for (int i = threadIdx.x; i < NBKT; i += 256) histM[c * NBKT + i] = h[i];
}

// ---------------- pass A2: per-bucket scan over chunks + graph segment starts ----------
__global__ void k_scan_gstart(int* __restrict__ histM, int* __restrict__ tot,
                              const int* __restrict__ batch, int* __restrict__ gst, int n) {
    int bi = blockIdx.x;
    if (bi < 4) {
        int b = bi * 256 + threadIdx.x;
        if (b >= NBKT) return;
        int running = 0;
        for (int c = 0; c < NCH; c += 8) {      // 8 loads in flight (NCH % 8 == 0)
            int i0 = (c + 0) * NBKT + b, i1 = (c + 1) * NBKT + b;
            int i2 = (c + 2) * NBKT + b, i3 = (c + 3) * NBKT + b;
            int i4 = (c + 4) * NBKT + b, i5 = (c + 5) * NBKT + b;
            int i6 = (c + 6) * NBKT + b, i7 = (c + 7) * NBKT + b;
            int v0 = histM[i0], v1 = histM[i1], v2 = histM[i2], v3 = histM[i3];
            int v4 = histM[i4], v5 = histM[i5], v6 = histM[i6], v7 = histM[i7];
            histM[i0] = running; running += v0;
            histM[i1] = running; running += v1;
            histM[i2] = running; running += v2;
            histM[i3] = running; running += v3;
            histM[i4] = running; running += v4;
            histM[i5] = running; running += v5;
            histM[i6] = running; running += v6;
            histM[i7] = running; running += v7;
        }
        tot[b] = running;
    } else {
        int i = (bi - 4) * 256 + threadIdx.x;
        if (i >= n) return;
        int b = batch[i];
        int pb = (i == 0) ? -1 : batch[i - 1];
        for (int g = pb + 1; g <= b; ++g) gst[g] = i;
        if (i == n - 1) for (int g = b + 1; g <= N_GRAPHS; ++g) gst[g] = n;
    }
}

// ---------------- pass A3: fill bucket entries (LDS rank atomics, no global atomics) ----
__global__ void __launch_bounds__(256) k_fill(const int* __restrict__ src,
                                              const int* __restrict__ dst,
                                              const float* __restrict__ ew,
                                              const int* __restrict__ histM,
                                              int2* __restrict__ bkt, int E) {
    __shared__ int h[NBKT];
    int c = (blockIdx.x & 7) * CPX + (blockIdx.x >> 3);
    for (int i = threadIdx.x; i < NBKT; i += 256) h[i] = 0;
    __syncthreads();
    int b0 = c * EPB;
    const int* bas = histM + c * NBKT;      // this chunk's per-bucket base (3 KB, L1-hot)
    for (int i = threadIdx.x; i < EPB; i += 256) {
        int e = b0 + i;
        if (e >= E) continue;
        int d = dst[e];
        int b = d >> 7;
        int r = atomicAdd(&h[b], 1);        // LDS atomic: rank within (chunk, bucket)
        int pos = bas[b] + r;
        if (pos < BKT_CAP) {
            int2 p;
            p.x = src[e] | ((d & 127) << 17);   // src < 2^17, dst low bits 17..23
            p.y = __float_as_int(ew[e]);
            bkt[(size_t)b * BKT_CAP + pos] = p;
        }
    }
}

// ---------------- pass B1: per-bucket degree counting-sort renumber + prep ------------
// Counts per node from bkt; counting-sorts the bucket's nodes by degree (49 bins) so
// each 8-node group has near-uniform degree (cuts round inflation 20 -> ~13).
// Writes: permidx[v] (orig -> new id, bucket-local), dinvN/xs (new numbering),
// rnd[g] = round4(group max degree), and ZERO-FILLS csr slots [deg, R) per node.
__global__ void __launch_bounds__(256) k_prep(
        const int* __restrict__ tot, const int2* __restrict__ bkt,
        const float* __restrict__ x,
        int* __restrict__ permidx, float* __restrict__ dinvN,
        float* __restrict__ xs, int* __restrict__ rnd,
        unsigned* __restrict__ csr, int n) {
    __shared__ int lc[128];
    __shared__ float ld[128];
    __shared__ int dh[NDEG];
    __shared__ int gmax[16];
    int b = blockIdx.x, tid = threadIdx.x;
    if (tid < 128) { lc[tid] = 0; ld[tid] = 0.f; }
    if (tid < NDEG) dh[tid] = 0;
    if (tid < 16) gmax[tid] = 0;
    __syncthreads();
    int m = min(tot[b], BKT_CAP);
    const int2* sb = bkt + (size_t)b * BKT_CAP;
    for (int i = tid; i < m; i += 256) {
        int2 p = sb[i];
        int low = (p.x >> 17) & 127;
        atomicAdd(&lc[low], 1);
        atomicAdd(&ld[low], __int_as_float(p.y));   // deg counts ALL edges (fp32)
    }
    __syncthreads();
    int nbase = b << 7;
    int nvalid = min(128, n - nbase);
    int c = 0;
    if (tid < nvalid) { c = min(lc[tid], CAP); atomicAdd(&dh[c], 1); }
    __syncthreads();
    if (tid == 0) {                          // exclusive prefix over 49 bins
        int run = 0;
        for (int d = 0; d < NDEG; ++d) { int t = dh[d]; dh[d] = run; run += t; }
    }
    __syncthreads();
    if (tid < nvalid) {
        int r = atomicAdd(&dh[c], 1);        // degree-sorted local position
        int ni = nbase + r;                  // new id (bucket-local renumber)
        int v = nbase + tid;                 // original id
        permidx[v] = ni;
        float di = rsqrtf(ld[tid] + 1.0f);   // +1 self-loop
        dinvN[ni] = di;
        #pragma unroll
        for (int c2 = 0; c2 < 10; ++c2) xs[ni * 16 + c2] = di * x[v * 10 + c2];
        #pragma unroll
        for (int c2 = 10; c2 < 16; ++c2) xs[ni * 16 + c2] = 0.f;
        atomicMax(&gmax[r >> 3], c);
        lc[tid] = (r << 8) | c;              // stash for zero-fill (lc free now)
    }
    __syncthreads();
    if (tid < 16 && (tid << 3) < nvalid)
        rnd[(b << 4) + tid] = (gmax[tid] + 3) & ~3;   // <= CAP=48
    if (tid < nvalid) {
        int rc = lc[tid];
        int r = rc >> 8, c2 = rc & 255;
        int R = (gmax[r >> 3] + 3) & ~3;
        int ni = nbase + r;
        size_t gb = (size_t)(ni >> 3) * GSTRIDE;
        int p8 = ni & 7;
        for (int e = c2; e < R; ++e)         // disjoint from k_build2's slots [0, deg)
            csr[gb + (e >> 2) * 32 + p8 * 4 + (e & 3)] = 0u;
    }
}

// ---------------- pass B2: bucket -> permuted group-interleaved CSR --------------------
// Entry (new id ni, slot e) at (ni>>3)*GSTRIDE + (e>>2)*32 + (ni&7)*4 + (e&3);
// src field remapped through permidx so layers run wholly in the new numbering.
__global__ void __launch_bounds__(256) k_build2(
        const int* __restrict__ tot, const int2* __restrict__ bkt,
        const int* __restrict__ permidx, unsigned* __restrict__ csr, int n) {
    __shared__ int lcur[128];
    __shared__ int pix[128];
    int b = blockIdx.x, tid = threadIdx.x;
    if (tid < 128) {
        lcur[tid] = 0;
        int v = (b << 7) + tid;
        pix[tid] = (v < n) ? permidx[v] : 0;
    }
    __syncthreads();
    int m = min(tot[b], BKT_CAP);
    const int2* sb = bkt + (size_t)b * BKT_CAP;
    for (int i = tid; i < m; i += 256) {
        int2 p = sb[i];
        int srcv = p.x & 0x1FFFF;
        int low = (p.x >> 17) & 127;
        int pos = atomicAdd(&lcur[low], 1);
        if (pos < CAP) {
            unsigned w15 = (unsigned)(int)rintf(__int_as_float(p.y) * 32767.f);
            int ni = pix[low];
            unsigned srcN = (unsigned)permidx[srcv];   // 400 KB table, L2-resident
            size_t idx = (size_t)(ni >> 3) * GSTRIDE + (pos >> 2) * 32 + (ni & 7) * 4 + (pos & 3);
            csr[idx] = srcN | (w15 << 17);
        }
    }
}

// ---------------- fused layer (scaled-H; group-interleaved read-only CSR) --------------
// UNCHANGED from r17 -- operates entirely in the degree-sorted numbering.
template<bool FIRST, bool SCALE_OUT>
__global__ void __launch_bounds__(256) k_layer(
        const void* __restrict__ HinV, const float* __restrict__ W,
        const float* __restrict__ bias,
        const unsigned* __restrict__ csr, const int* __restrict__ rnd,
        const float* __restrict__ dinv,
        __half* __restrict__ Hout, int n) {
    constexpr int WIN = FIRST ? 10 : 60;
    constexpr int WINP = FIRST ? 12 : 60;      // padded row count (quad multiple)
    const float*  Hf = (const float*)HinV;     // FIRST path (xs, stride 16)
    const __half* Hh = (const __half*)HinV;    // !FIRST path (S, stride 64)
    __shared__ float Ws[WINP * 64];            // Ws[k*64+j] = W[k][j]; pads -> 0
    __shared__ __align__(16) float accS[4][NPW][64];   // per-wave: same-wave RAW only
    for (int i = threadIdx.x; i < WINP * 64; i += 256) {
        int k = i >> 6, j = i & 63;
        Ws[i] = (j < F && k < WIN) ? W[k * F + j] : 0.f;
    }

    int wave = threadIdx.x >> 6;
    int lane = threadIdx.x & 63;
    float bj = (lane < F) ? bias[lane] : 0.f;
    int base = (blockIdx.x * 4 + wave) * NPW;  // grid exact: base+NPW-1 < n always
    int g = base >> 3;                         // wave's group
    const unsigned* segG = csr + (size_t)g * GSTRIDE;
    int mu = rnd[g];                           // wave-uniform round bound (multiple of 4)

    if constexpr (FIRST) {
        __syncthreads();                       // Ws ready
        int l16 = lane & 15;                   // feature (xs padded: 10-15 are zero)
        int qt = lane >> 4;                    // quarter -> node within quad
        float a0 = Hf[(base + qt) * 16 + l16];       // self terms (pre-scaled xs)
        float a1 = Hf[(base + 4 + qt) * 16 + l16];
        for (int e = 0; e < mu; e += 4) {      // 8 gathers in flight (both quads)
            const unsigned* ch = segG + (e >> 2) * 32;
            uint4 qa = *(const uint4*)(ch + qt * 4);
            uint4 qb = *(const uint4*)(ch + (4 + qt) * 4);
            float x0 = Hf[(qa.x & 0x1FFFF) * 16 + l16];
            float x1 = Hf[(qa.y & 0x1FFFF) * 16 + l16];
            float x2 = Hf[(qa.z & 0x1FFFF) * 16 + l16];
            float x3 = Hf[(qa.w & 0x1FFFF) * 16 + l16];
            float y0 = Hf[(qb.x & 0x1FFFF) * 16 + l16];
            float y1 = Hf[(qb.y & 0x1FFFF) * 16 + l16];
            float y2 = Hf[(qb.z & 0x1FFFF) * 16 + l16];
            float y3 = Hf[(qb.w & 0x1FFFF) * 16 + l16];
            a0 = fmaf((float)(qa.x >> 17) * WSC, x0, a0);
            a0 = fmaf((float)(qa.y >> 17) * WSC, x1, a0);
            a0 = fmaf((float)(qa.z >> 17) * WSC, x2, a0);
            a0 = fmaf((float)(qa.w >> 17) * WSC, x3, a0);
            a1 = fmaf((float)(qb.x >> 17) * WSC, y0, a1);
            a1 = fmaf((float)(qb.y >> 17) * WSC, y1, a1);
            a1 = fmaf((float)(qb.z >> 17) * WSC, y2, a1);
            a1 = fmaf((float)(qb.w >> 17) * WSC, y3, a1);
        }
        accS[wave][qt][l16]     = a0 * dinv[base + qt];       // same-wave writes
        accS[wave][4 + qt][l16] = a1 * dinv[base + 4 + qt];   // f10-15 = exact 0
        float o[NPW];
        #pragma unroll
        for (int t = 0; t < NPW; ++t) o[t] = bj;
        const float4* aq = (const float4*)&accS[wave][0][0];   // [NPW][16 quads]
        #pragma unroll
        for (int kq = 0; kq < 3; ++kq) {
            float w0 = Ws[(4 * kq + 0) * 64 + lane];
            float w1 = Ws[(4 * kq + 1) * 64 + lane];
            float w2 = Ws[(4 * kq + 2) * 64 + lane];
            float w3 = Ws[(4 * kq + 3) * 64 + lane];
            #pragma unroll
            for (int t = 0; t < NPW; ++t) {
                float4 aa = aq[t * 16 + kq];   // uniform addr -> broadcast, conflict-free
                o[t] = fmaf(aa.x, w0, o[t]);
                o[t] = fmaf(aa.y, w1, o[t]);
                o[t] = fmaf(aa.z, w2, o[t]);   // rows 10,11: Ws = 0
                o[t] = fmaf(aa.w, w3, o[t]);
            }
        }
        #pragma unroll
        for (int t = 0; t < NPW; ++t) {
            float sc = SCALE_OUT ? dinv[base + t] : 1.f;
            Hout[(size_t)(base + t) * 64 + lane] = __float2half_rn(fmaxf(o[t], 0.f) * sc);
        }
    } else {
        __syncthreads();                       // Ws ready
        int h  = lane >> 5;                    // which node of the pair
        int lh = lane & 31;
        int fo = lh * 2;                       // feature offset (pairs; lh>=30 -> pad zeros)

        float2 acc2[4];
        float dis[4];
        #pragma unroll
        for (int p = 0; p < 4; ++p) {
            int v = base + 2 * p + h;
            dis[p] = dinv[v];
            __half2 sh = *(const __half2*)(Hh + (size_t)v * 64 + fo);
            acc2[p].x = __low2float(sh);       // self term: S[v] (scaled storage)
            acc2[p].y = __high2float(sh);
        }

        for (int e = 0; e < mu; e += 4) {      // joint rounds: 16 gathers in flight
            const unsigned* ch = segG + (e >> 2) * 32;
            uint4 q[4];
            #pragma unroll
            for (int p = 0; p < 4; ++p) q[p] = *(const uint4*)(ch + (2 * p + h) * 4);
            #pragma unroll
            for (int p = 0; p < 4; ++p) {
                unsigned e0 = q[p].x, e1 = q[p].y, e2 = q[p].z, e3 = q[p].w;
                __half2 g0 = *(const __half2*)(Hh + (size_t)(e0 & 0x1FFFF) * 64 + fo);
                __half2 g1 = *(const __half2*)(Hh + (size_t)(e1 & 0x1FFFF) * 64 + fo);
                __half2 g2 = *(const __half2*)(Hh + (size_t)(e2 & 0x1FFFF) * 64 + fo);
                __half2 g3 = *(const __half2*)(Hh + (size_t)(e3 & 0x1FFFF) * 64 + fo);
                float w0 = (float)(e0 >> 17) * WSC;
                float w1 = (float)(e1 >> 17) * WSC;
                float w2 = (float)(e2 >> 17) * WSC;
                float w3 = (float)(e3 >> 17) * WSC;
                acc2[p].x = fmaf(w0, __low2float(g0), acc2[p].x);
                acc2[p].y = fmaf(w0, __high2float(g0), acc2[p].y);
                acc2[p].x = fmaf(w1, __low2float(g1), acc2[p].x);
                acc2[p].y = fmaf(w1, __high2float(g1), acc2[p].y);
                acc2[p].x = fmaf(w2, __low2float(g2), acc2[p].x);
                acc2[p].y = fmaf(w2, __high2float(g2), acc2[p].y);
                acc2[p].x = fmaf(w3, __low2float(g3), acc2[p].x);
                acc2[p].y = fmaf(w3, __high2float(g3), acc2[p].y);
            }
        }
        #pragma unroll
        for (int p = 0; p < 4; ++p) {          // agg = dinv[v] * (sum + S[v])
            acc2[p].x *= dis[p]; acc2[p].y *= dis[p];
            *(float2*)&accS[wave][2 * p + h][fo] = acc2[p];   // same-wave write
        }

        // phase 2: broadcast MM -- no block barrier (same-wave LDS RAW, lgkmcnt-ordered)
        float o[NPW];
        #pragma unroll
        for (int t = 0; t < NPW; ++t) o[t] = bj;
        const float4* aq = (const float4*)&accS[wave][0][0];   // [NPW][16 quads]
        #pragma unroll
        for (int kq = 0; kq < 15; ++kq) {
            float w0 = Ws[(4 * kq + 0) * 64 + lane];
            float w1 = Ws[(4 * kq + 1) * 64 + lane];
            float w2 = Ws[(4 * kq + 2) * 64 + lane];
            float w3 = Ws[(4 * kq + 3) * 64 + lane];
            #pragma unroll
            for (int t = 0; t < NPW; ++t) {
                float4 aa = aq[t * 16 + kq];   // uniform addr -> broadcast, conflict-free
                o[t] = fmaf(aa.x, w0, o[t]);
                o[t] = fmaf(aa.y, w1, o[t]);
                o[t] = fmaf(aa.z, w2, o[t]);
                o[t] = fmaf(aa.w, w3, o[t]);
            }
        }
        #pragma unroll
        for (int t = 0; t < NPW; ++t) {
            float sc = SCALE_OUT ? dinv[base + t] : 1.f;
            Hout[(size_t)(base + t) * 64 + lane] = __float2half_rn(fmaxf(o[t], 0.f) * sc);
        }
    }
}

// ---------------- fused segment-max pool + MLP head: one block per graph ----------------
// H is in the degree-sorted numbering -> wave-uniform permidx indirection per node.
__global__ void __launch_bounds__(256) k_poolmlp(
        const __half* __restrict__ H, const int* __restrict__ start,
        const int* __restrict__ permidx,
        const float* __restrict__ L1w, const float* __restrict__ L1b,
        const float* __restrict__ L2w, const float* __restrict__ L2b,
        const float* __restrict__ L3w, const float* __restrict__ L3b,
        float* __restrict__ out) {
    __shared__ float red[4 * F];
    __shared__ float gin[F], h1[F], h2[10];
    int gi = blockIdx.x;
    int wave = threadIdx.x >> 6;
    int lane = threadIdx.x & 63;
    int t = threadIdx.x;
    int s = start[gi], e = start[gi + 1];
    float m = 0.f;                       // relu output >= 0; empty graph -> 0 (matches ref guard)
    for (int i = s + wave; i < e; i += 4) {
        int ni = permidx[i];             // wave-uniform -> broadcast load
        m = fmaxf(m, __half2float(H[(size_t)ni * 64 + lane]));
    }
    if (lane < F) red[wave * F + lane] = m;
    __syncthreads();
    if (t < F)
        gin[t] = fmaxf(fmaxf(red[t], red[F + t]), fmaxf(red[2 * F + t], red[3 * F + t]));
    __syncthreads();
    if (t < F) {
        float a = L1b[t];
        for (int k = 0; k < F; ++k) a += gin[k] * L1w[k * F + t];
        h1[t] = fmaxf(a, 0.f);
    }
    __syncthreads();
    if (t < 10) {
        float a = L2b[t];
        for (int k = 0; k < F; ++k) a += h1[k] * L2w[k * 10 + t];
        h2[t] = fmaxf(a, 0.f);
    }
    __syncthreads();
    if (t < 2) {
        float a = L3b[t];
        for (int k = 0; k < 10; ++k) a += h2[k] * L3w[k * 2 + t];
        out[gi * 2 + t] = a;
    }
}

extern "C" void kernel_launch(void* const* d_in, const int* in_sizes, int n_in,
                              void* d_out, int out_size, void* d_ws, size_t ws_size,
                              hipStream_t stream) {
    const int n = N_NODES, E = N_EDGES;
    const float* x   = (const float*)d_in[0];
    const int* ei    = (const int*)d_in[1];         // [2, E]
    const int* batch = (const int*)d_in[2];
    const float* ew  = (const float*)d_in[3];
    const float* W1 = (const float*)d_in[4],  *b1 = (const float*)d_in[5];
    const float* W2 = (const float*)d_in[6],  *b2 = (const float*)d_in[7];
    const float* W3 = (const float*)d_in[8],  *b3 = (const float*)d_in[9];
    const float* W4 = (const float*)d_in[10], *b4 = (const float*)d_in[11];
    const float* L1w = (const float*)d_in[12], *L1b = (const float*)d_in[13];
    const float* L2w = (const float*)d_in[14], *L2b = (const float*)d_in[15];
    const float* L3w = (const float*)d_in[16], *L3b = (const float*)d_in[17];
    float* out = (float*)d_out;

    const int* src = ei;
    const int* dst = ei + E;

    // ---- workspace carve (256B aligned) ----
    char* ws = (char*)d_ws;
    size_t off = 0;
    auto carve = [&](size_t bytes) {
        void* p = ws + off;
        off += (bytes + 255) & ~size_t(255);
        return p;
    };
    int*      rnd   = (int*)carve((n / 8) * 4);                // per-group round bound
    float*    dinvN = (float*)carve(n * 4);                    // new numbering
    int*      permidx = (int*)carve(n * 4);                    // orig -> new id
    int*      gst   = (int*)carve((N_GRAPHS + 1) * 4);
    unsigned* csr   = (unsigned*)carve((size_t)n * CAP * 4);   // permuted group-interleaved
    int2*     bkt   = (int2*)carve((size_t)NBKT * BKT_CAP * 8);  // 12.8 MB bucket entries
    int*      histM = (int*)carve((size_t)NCH * NBKT * 4);     // chunk histograms -> bases
    int*      tot   = (int*)carve(NBKT * 4);
    float*    xs    = (float*)carve((size_t)n * 16 * 4);       // dinv-scaled padded x (new numbering)
    __half*   hA    = (__half*)carve((size_t)n * 64 * 2);      // fp16 S / H rows
    __half*   hB    = (__half*)carve((size_t)n * 64 * 2);
    (void)ws_size;

    const int NB = (n + 255) / 256;                   // 391
    const int LB = n / (4 * NPW);                     // 3125, exact

    // ---- CSR build: hist -> scan+gstart -> fill -> degree-sort prep -> scatter ----
    k_hist<<<NCH, 256, 0, stream>>>(dst, histM, E);
    k_scan_gstart<<<4 + NB, 256, 0, stream>>>(histM, tot, batch, gst, n);
    k_fill<<<NCH, 256, 0, stream>>>(src, dst, ew, histM, bkt, E);
    k_prep<<<NBKT, 256, 0, stream>>>(tot, bkt, x, permidx, dinvN, xs, rnd, csr, n);
    k_build2<<<NBKT, 256, 0, stream>>>(tot, bkt, permidx, csr, n);

    // ---- 4 fused GCN layers (scaled-H; layer 4 stores unscaled for pooling) ----
    k_layer<true,  true ><<<LB, 256, 0, stream>>>(xs, W1, b1, csr, rnd, dinvN, hA, n);
    k_layer<false, true ><<<LB, 256, 0, stream>>>(hA, W2, b2, csr, rnd, dinvN, hB, n);
    k_layer<false, true ><<<LB, 256, 0, stream>>>(hB, W3, b3, csr, rnd, dinvN, hA, n);
    k_layer<false, false><<<LB, 256, 0, stream>>>(hA, W4, b4, csr, rnd, dinvN, hB, n);

    // ---- fused segment max pool + MLP (permidx indirection) ----
    k_poolmlp<<<N_GRAPHS, 256, 0, stream>>>(hB, gst, permidx,
                                            L1w, L1b, L2w, L2b, L3w, L3b, out);
}

// Round 19
// 223.631 us; speedup vs baseline: 1.0739x; 1.0739x over previous
//
#include <hip/hip_runtime.h>
#include <hip/hip_fp16.h>

#define N_NODES 100000
#define N_EDGES 1200000
#define N_GRAPHS 512
#define F 60
#define NPW 8      // nodes per wave in k_layer == group size (100000 % 8 == 0 -> exact)
#define CAP 48     // padded CSR slots per node (Poisson(12): P(deg>=48)*N ~ 3e-10; held r2-r16)
#define GSTRIDE 384 // CAP * 8 entries per group
#define NBKT 782   // node buckets of 128 (ceil(100000/128))
#define EPB 4096   // edges per chunk
#define CPX 37     // chunks per XCD group
#define NCH 296    // chunks total (8 * 37; NCH*EPB >= E)
#define BKT_CAP 2048 // per-bucket entry capacity (mean 1534, sigma 39 -> +13 sigma)
#define WSC 3.0518509e-05f   // 1/32767: 15-bit fixed-point weight decode

// ---------------- pass A1: per-chunk histogram over dst buckets (LDS atomics only) ----
__global__ void __launch_bounds__(256) k_hist(const int* __restrict__ dst,
                                              int* __restrict__ histM, int E) {
    __shared__ int h[NBKT];
    int c = (blockIdx.x & 7) * CPX + (blockIdx.x >> 3);   // XCD-grouped chunk id
    for (int i = threadIdx.x; i < NBKT; i += 256) h[i] = 0;
    __syncthreads();
    int b0 = c * EPB;
    for (int i = threadIdx.x; i < EPB; i += 256) {
        int e = b0 + i;
        if (e < E) atomicAdd(&h[dst[e] >> 7], 1);
    }
    __syncthreads();
    for (int i = threadIdx.x; i < NBKT; i += 256) histM[c * NBKT + i] = h[i];
}

// ---------------- pass A2: per-bucket scan over chunks + graph segment starts ----------
__global__ void k_scan_gstart(int* __restrict__ histM, int* __restrict__ tot,
                              const int* __restrict__ batch, int* __restrict__ gst, int n) {
    int bi = blockIdx.x;
    if (bi < 4) {
        int b = bi * 256 + threadIdx.x;
        if (b >= NBKT) return;
        int running = 0;
        for (int c = 0; c < NCH; c += 8) {      // 8 loads in flight (NCH % 8 == 0)
            int i0 = (c + 0) * NBKT + b, i1 = (c + 1) * NBKT + b;
            int i2 = (c + 2) * NBKT + b, i3 = (c + 3) * NBKT + b;
            int i4 = (c + 4) * NBKT + b, i5 = (c + 5) * NBKT + b;
            int i6 = (c + 6) * NBKT + b, i7 = (c + 7) * NBKT + b;
            int v0 = histM[i0], v1 = histM[i1], v2 = histM[i2], v3 = histM[i3];
            int v4 = histM[i4], v5 = histM[i5], v6 = histM[i6], v7 = histM[i7];
            histM[i0] = running; running += v0;
            histM[i1] = running; running += v1;
            histM[i2] = running; running += v2;
            histM[i3] = running; running += v3;
            histM[i4] = running; running += v4;
            histM[i5] = running; running += v5;
            histM[i6] = running; running += v6;
            histM[i7] = running; running += v7;
        }
        tot[b] = running;
    } else {
        int i = (bi - 4) * 256 + threadIdx.x;
        if (i >= n) return;
        int b = batch[i];
        int pb = (i == 0) ? -1 : batch[i - 1];
        for (int g = pb + 1; g <= b; ++g) gst[g] = i;
        if (i == n - 1) for (int g = b + 1; g <= N_GRAPHS; ++g) gst[g] = n;
    }
}

// ---------------- pass A3: fill bucket entries (LDS rank atomics, no global atomics) ----
__global__ void __launch_bounds__(256) k_fill(const int* __restrict__ src,
                                              const int* __restrict__ dst,
                                              const float* __restrict__ ew,
                                              const int* __restrict__ histM,
                                              int2* __restrict__ bkt, int E) {
    __shared__ int h[NBKT];
    int c = (blockIdx.x & 7) * CPX + (blockIdx.x >> 3);
    for (int i = threadIdx.x; i < NBKT; i += 256) h[i] = 0;
    __syncthreads();
    int b0 = c * EPB;
    const int* bas = histM + c * NBKT;      // this chunk's per-bucket base (3 KB, L1-hot)
    for (int i = threadIdx.x; i < EPB; i += 256) {
        int e = b0 + i;
        if (e >= E) continue;
        int d = dst[e];
        int b = d >> 7;
        int r = atomicAdd(&h[b], 1);        // LDS atomic: rank within (chunk, bucket)
        int pos = bas[b] + r;
        if (pos < BKT_CAP) {
            int2 p;
            p.x = src[e] | ((d & 127) << 17);   // src < 2^17, dst low bits 17..23
            p.y = __float_as_int(ew[e]);
            bkt[(size_t)b * BKT_CAP + pos] = p;
        }
    }
}

// ---------------- pass B: bucket -> group-interleaved CSR, fused deg + xs + rnd -------
// CSR layout (4 B entries {src:17 | w15:15}): group g = v>>3 owns GSTRIDE entries;
// entry (v, slot e) at g*GSTRIDE + (e>>2)*32 + (v&7)*4 + (e&3)  -- one fully-used
// 128 B line per 4-slot round per group, read sequentially by the layers.
// ZERO-FILLS slots [m, R) where R = round4(max count over the 8-node group); writes
// rnd[g] = R. Also writes xs[v][0..15] = dinv[v]*x[v][0..9] (zero-padded).
__global__ void __launch_bounds__(256) k_build(
        const int* __restrict__ tot, const int2* __restrict__ bkt,
        unsigned* __restrict__ csr, int* __restrict__ rnd,
        float* __restrict__ dinv, const float* __restrict__ x,
        float* __restrict__ xs, int n) {
    __shared__ int lcur[128];
    __shared__ float ldeg[128];
    int b = blockIdx.x, tid = threadIdx.x;
    if (tid < 128) { lcur[tid] = 0; ldeg[tid] = 0.f; }
    __syncthreads();
    int nbase = b << 7;
    int m = min(tot[b], BKT_CAP);
    const int2* sb = bkt + (size_t)b * BKT_CAP;
    for (int i = tid; i < m; i += 256) {
        int2 p = sb[i];
        int srcv = p.x & 0x1FFFF;
        int low = (p.x >> 17) & 127;
        int pos = atomicAdd(&lcur[low], 1);
        if (pos < CAP) {
            unsigned w15 = (unsigned)(int)rintf(__int_as_float(p.y) * 32767.f);
            int v = nbase + low;
            size_t idx = (size_t)(v >> 3) * GSTRIDE + (pos >> 2) * 32 + (v & 7) * 4 + (pos & 3);
            csr[idx] = (unsigned)srcv | (w15 << 17);
        }
        atomicAdd(&ldeg[low], __int_as_float(p.y));   // deg counts ALL edges (fp32)
    }
    __syncthreads();
    if (tid < 128) {
        int v = nbase + tid;
        if (v < n) {      // n % 8 == 0 -> groups of 8 are fully valid or fully out
            int mA = min(lcur[tid], CAP);
            float di = rsqrtf(ldeg[tid] + 1.0f);          // +1 self-loop
            dinv[v] = di;
            // pre-scaled, padded layer-1 input
            #pragma unroll
            for (int c2 = 0; c2 < 10; ++c2) xs[v * 16 + c2] = di * x[v * 10 + c2];
            #pragma unroll
            for (int c2 = 10; c2 < 16; ++c2) xs[v * 16 + c2] = 0.f;
            // group round bound + zero-fill
            int g0 = tid & ~7;
            int m8 = 0;
            #pragma unroll
            for (int i2 = 0; i2 < 8; ++i2) m8 = max(m8, min(lcur[g0 + i2], CAP));
            int R = (m8 + 3) & ~3;                        // <= CAP=48
            size_t gb = (size_t)(v >> 3) * GSTRIDE;
            int p8 = v & 7;
            for (int e = mA; e < R; ++e)
                csr[gb + (e >> 2) * 32 + p8 * 4 + (e & 3)] = 0u;
            if ((tid & 7) == 0) rnd[v >> 3] = R;
        }
    }
}

// ---------------- fused layer (scaled-H; group-interleaved read-only CSR) --------------
// S[v] = dinv[v]*H[v] (fp16) for layers 1-3:
//   agg[v] = dinv[v] * ( sum_e w_e * S[src_e] + S[v] ),  w_e = (entry>>17)*WSC.
// One wave == one 8-node group; per round it streams ONE fully-used 128 B CSR chunk.
// FIRST: quarter-wave per node (fp32 xs gathers); !FIRST: paired half-wave, 16 gathers
// in flight; phase-2 = broadcast MM via per-wave accS (same-wave LDS RAW, no barrier).
template<bool FIRST, bool SCALE_OUT>
__global__ void __launch_bounds__(256) k_layer(
        const void* __restrict__ HinV, const float* __restrict__ W,
        const float* __restrict__ bias,
        const unsigned* __restrict__ csr, const int* __restrict__ rnd,
        const float* __restrict__ dinv,
        __half* __restrict__ Hout, int n) {
    constexpr int WIN = FIRST ? 10 : 60;
    constexpr int WINP = FIRST ? 12 : 60;      // padded row count (quad multiple)
    const float*  Hf = (const float*)HinV;     // FIRST path (xs, stride 16)
    const __half* Hh = (const __half*)HinV;    // !FIRST path (S, stride 64)
    __shared__ float Ws[WINP * 64];            // Ws[k*64+j] = W[k][j]; pads -> 0
    __shared__ __align__(16) float accS[4][NPW][64];   // per-wave: same-wave RAW only
    for (int i = threadIdx.x; i < WINP * 64; i += 256) {
        int k = i >> 6, j = i & 63;
        Ws[i] = (j < F && k < WIN) ? W[k * F + j] : 0.f;
    }

    int wave = threadIdx.x >> 6;
    int lane = threadIdx.x & 63;
    float bj = (lane < F) ? bias[lane] : 0.f;
    int base = (blockIdx.x * 4 + wave) * NPW;  // grid exact: base+NPW-1 < n always
    int g = base >> 3;                         // wave's group
    const unsigned* segG = csr + (size_t)g * GSTRIDE;
    int mu = rnd[g];                           // wave-uniform round bound (multiple of 4)

    if constexpr (FIRST) {
        __syncthreads();                       // Ws ready
        int l16 = lane & 15;                   // feature (xs padded: 10-15 are zero)
        int qt = lane >> 4;                    // quarter -> node within quad
        float a0 = Hf[(base + qt) * 16 + l16];       // self terms (pre-scaled xs)
        float a1 = Hf[(base + 4 + qt) * 16 + l16];
        for (int e = 0; e < mu; e += 4) {      // 8 gathers in flight (both quads)
            const unsigned* ch = segG + (e >> 2) * 32;
            uint4 qa = *(const uint4*)(ch + qt * 4);
            uint4 qb = *(const uint4*)(ch + (4 + qt) * 4);
            float x0 = Hf[(qa.x & 0x1FFFF) * 16 + l16];
            float x1 = Hf[(qa.y & 0x1FFFF) * 16 + l16];
            float x2 = Hf[(qa.z & 0x1FFFF) * 16 + l16];
            float x3 = Hf[(qa.w & 0x1FFFF) * 16 + l16];
            float y0 = Hf[(qb.x & 0x1FFFF) * 16 + l16];
            float y1 = Hf[(qb.y & 0x1FFFF) * 16 + l16];
            float y2 = Hf[(qb.z & 0x1FFFF) * 16 + l16];
            float y3 = Hf[(qb.w & 0x1FFFF) * 16 + l16];
            a0 = fmaf((float)(qa.x >> 17) * WSC, x0, a0);
            a0 = fmaf((float)(qa.y >> 17) * WSC, x1, a0);
            a0 = fmaf((float)(qa.z >> 17) * WSC, x2, a0);
            a0 = fmaf((float)(qa.w >> 17) * WSC, x3, a0);
            a1 = fmaf((float)(qb.x >> 17) * WSC, y0, a1);
            a1 = fmaf((float)(qb.y >> 17) * WSC, y1, a1);
            a1 = fmaf((float)(qb.z >> 17) * WSC, y2, a1);
            a1 = fmaf((float)(qb.w >> 17) * WSC, y3, a1);
        }
        accS[wave][qt][l16]     = a0 * dinv[base + qt];       // same-wave writes
        accS[wave][4 + qt][l16] = a1 * dinv[base + 4 + qt];   // f10-15 = exact 0
        float o[NPW];
        #pragma unroll
        for (int t = 0; t < NPW; ++t) o[t] = bj;
        const float4* aq = (const float4*)&accS[wave][0][0];   // [NPW][16 quads]
        #pragma unroll
        for (int kq = 0; kq < 3; ++kq) {
            float w0 = Ws[(4 * kq + 0) * 64 + lane];
            float w1 = Ws[(4 * kq + 1) * 64 + lane];
            float w2 = Ws[(4 * kq + 2) * 64 + lane];
            float w3 = Ws[(4 * kq + 3) * 64 + lane];
            #pragma unroll
            for (int t = 0; t < NPW; ++t) {
                float4 aa = aq[t * 16 + kq];   // uniform addr -> broadcast, conflict-free
                o[t] = fmaf(aa.x, w0, o[t]);
                o[t] = fmaf(aa.y, w1, o[t]);
                o[t] = fmaf(aa.z, w2, o[t]);   // rows 10,11: Ws = 0
                o[t] = fmaf(aa.w, w3, o[t]);
            }
        }
        #pragma unroll
        for (int t = 0; t < NPW; ++t) {
            float sc = SCALE_OUT ? dinv[base + t] : 1.f;
            Hout[(size_t)(base + t) * 64 + lane] = __float2half_rn(fmaxf(o[t], 0.f) * sc);
        }
    } else {
        __syncthreads();                       // Ws ready
        int h  = lane >> 5;                    // which node of the pair
        int lh = lane & 31;
        int fo = lh * 2;                       // feature offset (pairs; lh>=30 -> pad zeros)

        float2 acc2[4];
        float dis[4];
        #pragma unroll
        for (int p = 0; p < 4; ++p) {
            int v = base + 2 * p + h;
            dis[p] = dinv[v];
            __half2 sh = *(const __half2*)(Hh + (size_t)v * 64 + fo);
            acc2[p].x = __low2float(sh);       // self term: S[v] (scaled storage)
            acc2[p].y = __high2float(sh);
        }

        for (int e = 0; e < mu; e += 4) {      // joint rounds: 16 gathers in flight
            const unsigned* ch = segG + (e >> 2) * 32;
            uint4 q[4];
            #pragma unroll
            for (int p = 0; p < 4; ++p) q[p] = *(const uint4*)(ch + (2 * p + h) * 4);
            #pragma unroll
            for (int p = 0; p < 4; ++p) {
                unsigned e0 = q[p].x, e1 = q[p].y, e2 = q[p].z, e3 = q[p].w;
                __half2 g0 = *(const __half2*)(Hh + (size_t)(e0 & 0x1FFFF) * 64 + fo);
                __half2 g1 = *(const __half2*)(Hh + (size_t)(e1 & 0x1FFFF) * 64 + fo);
                __half2 g2 = *(const __half2*)(Hh + (size_t)(e2 & 0x1FFFF) * 64 + fo);
                __half2 g3 = *(const __half2*)(Hh + (size_t)(e3 & 0x1FFFF) * 64 + fo);
                float w0 = (float)(e0 >> 17) * WSC;
                float w1 = (float)(e1 >> 17) * WSC;
                float w2 = (float)(e2 >> 17) * WSC;
                float w3 = (float)(e3 >> 17) * WSC;
                acc2[p].x = fmaf(w0, __low2float(g0), acc2[p].x);
                acc2[p].y = fmaf(w0, __high2float(g0), acc2[p].y);
                acc2[p].x = fmaf(w1, __low2float(g1), acc2[p].x);
                acc2[p].y = fmaf(w1, __high2float(g1), acc2[p].y);
                acc2[p].x = fmaf(w2, __low2float(g2), acc2[p].x);
                acc2[p].y = fmaf(w2, __high2float(g2), acc2[p].y);
                acc2[p].x = fmaf(w3, __low2float(g3), acc2[p].x);
                acc2[p].y = fmaf(w3, __high2float(g3), acc2[p].y);
            }
        }
        #pragma unroll
        for (int p = 0; p < 4; ++p) {          // agg = dinv[v] * (sum + S[v])
            acc2[p].x *= dis[p]; acc2[p].y *= dis[p];
            *(float2*)&accS[wave][2 * p + h][fo] = acc2[p];   // same-wave write
        }

        // phase 2: broadcast MM -- no block barrier (same-wave LDS RAW, lgkmcnt-ordered)
        float o[NPW];
        #pragma unroll
        for (int t = 0; t < NPW; ++t) o[t] = bj;
        const float4* aq = (const float4*)&accS[wave][0][0];   // [NPW][16 quads]
        #pragma unroll
        for (int kq = 0; kq < 15; ++kq) {
            float w0 = Ws[(4 * kq + 0) * 64 + lane];
            float w1 = Ws[(4 * kq + 1) * 64 + lane];
            float w2 = Ws[(4 * kq + 2) * 64 + lane];
            float w3 = Ws[(4 * kq + 3) * 64 + lane];
            #pragma unroll
            for (int t = 0; t < NPW; ++t) {
                float4 aa = aq[t * 16 + kq];   // uniform addr -> broadcast, conflict-free
                o[t] = fmaf(aa.x, w0, o[t]);
                o[t] = fmaf(aa.y, w1, o[t]);
                o[t] = fmaf(aa.z, w2, o[t]);
                o[t] = fmaf(aa.w, w3, o[t]);
            }
        }
        #pragma unroll
        for (int t = 0; t < NPW; ++t) {
            float sc = SCALE_OUT ? dinv[base + t] : 1.f;
            Hout[(size_t)(base + t) * 64 + lane] = __float2half_rn(fmaxf(o[t], 0.f) * sc);
        }
    }
}

// ---------------- fused segment-max pool + MLP head: one block per graph ----------------
__global__ void __launch_bounds__(256) k_poolmlp(
        const __half* __restrict__ H, const int* __restrict__ start,
        const float* __restrict__ L1w, const float* __restrict__ L1b,
        const float* __restrict__ L2w, const float* __restrict__ L2b,
        const float* __restrict__ L3w, const float* __restrict__ L3b,
        float* __restrict__ out) {
    __shared__ float red[4 * F];
    __shared__ float gin[F], h1[F], h2[10];
    int gi = blockIdx.x;
    int wave = threadIdx.x >> 6;
    int lane = threadIdx.x & 63;
    int t = threadIdx.x;
    int s = start[gi], e = start[gi + 1];
    float m = 0.f;                       // relu output >= 0; empty graph -> 0 (matches ref guard)
    for (int i = s + wave; i < e; i += 4)
        m = fmaxf(m, __half2float(H[(size_t)i * 64 + lane]));
    if (lane < F) red[wave * F + lane] = m;
    __syncthreads();
    if (t < F)
        gin[t] = fmaxf(fmaxf(red[t], red[F + t]), fmaxf(red[2 * F + t], red[3 * F + t]));
    __syncthreads();
    if (t < F) {
        float a = L1b[t];
        for (int k = 0; k < F; ++k) a += gin[k] * L1w[k * F + t];
        h1[t] = fmaxf(a, 0.f);
    }
    __syncthreads();
    if (t < 10) {
        float a = L2b[t];
        for (int k = 0; k < F; ++k) a += h1[k] * L2w[k * 10 + t];
        h2[t] = fmaxf(a, 0.f);
    }
    __syncthreads();
    if (t < 2) {
        float a = L3b[t];
        for (int k = 0; k < 10; ++k) a += h2[k] * L3w[k * 2 + t];
        out[gi * 2 + t] = a;
    }
}

extern "C" void kernel_launch(void* const* d_in, const int* in_sizes, int n_in,
                              void* d_out, int out_size, void* d_ws, size_t ws_size,
                              hipStream_t stream) {
    const int n = N_NODES, E = N_EDGES;
    const float* x   = (const float*)d_in[0];
    const int* ei    = (const int*)d_in[1];         // [2, E]
    const int* batch = (const int*)d_in[2];
    const float* ew  = (const float*)d_in[3];
    const float* W1 = (const float*)d_in[4],  *b1 = (const float*)d_in[5];
    const float* W2 = (const float*)d_in[6],  *b2 = (const float*)d_in[7];
    const float* W3 = (const float*)d_in[8],  *b3 = (const float*)d_in[9];
    const float* W4 = (const float*)d_in[10], *b4 = (const float*)d_in[11];
    const float* L1w = (const float*)d_in[12], *L1b = (const float*)d_in[13];
    const float* L2w = (const float*)d_in[14], *L2b = (const float*)d_in[15];
    const float* L3w = (const float*)d_in[16], *L3b = (const float*)d_in[17];
    float* out = (float*)d_out;

    const int* src = ei;
    const int* dst = ei + E;

    // ---- workspace carve (256B aligned) ----
    char* ws = (char*)d_ws;
    size_t off = 0;
    auto carve = [&](size_t bytes) {
        void* p = ws + off;
        off += (bytes + 255) & ~size_t(255);
        return p;
    };
    int*      rnd   = (int*)carve((n / 8) * 4);                // per-group round bound
    float*    dinv  = (float*)carve(n * 4);
    int*      gst   = (int*)carve((N_GRAPHS + 1) * 4);
    unsigned* csr   = (unsigned*)carve((size_t)n * CAP * 4);   // group-interleaved packed
    int2*     bkt   = (int2*)carve((size_t)NBKT * BKT_CAP * 8);  // 12.8 MB bucket entries
    int*      histM = (int*)carve((size_t)NCH * NBKT * 4);     // chunk histograms -> bases
    int*      tot   = (int*)carve(NBKT * 4);
    float*    xs    = (float*)carve((size_t)n * 16 * 4);       // dinv-scaled padded x
    __half*   hA    = (__half*)carve((size_t)n * 64 * 2);      // fp16 S / H rows
    __half*   hB    = (__half*)carve((size_t)n * 64 * 2);
    (void)ws_size;

    const int NB = (n + 255) / 256;                   // 391
    const int LB = n / (4 * NPW);                     // 3125, exact

    // ---- CSR build: hist -> scan+gstart -> fill -> build (zero global atomics) ----
    k_hist<<<NCH, 256, 0, stream>>>(dst, histM, E);
    k_scan_gstart<<<4 + NB, 256, 0, stream>>>(histM, tot, batch, gst, n);
    k_fill<<<NCH, 256, 0, stream>>>(src, dst, ew, histM, bkt, E);
    k_build<<<NBKT, 256, 0, stream>>>(tot, bkt, csr, rnd, dinv, x, xs, n);

    // ---- 4 fused GCN layers (scaled-H; layer 4 stores unscaled for pooling) ----
    k_layer<true,  true ><<<LB, 256, 0, stream>>>(xs, W1, b1, csr, rnd, dinv, hA, n);
    k_layer<false, true ><<<LB, 256, 0, stream>>>(hA, W2, b2, csr, rnd, dinv, hB, n);
    k_layer<false, true ><<<LB, 256, 0, stream>>>(hB, W3, b3, csr, rnd, dinv, hA, n);
    k_layer<false, false><<<LB, 256, 0, stream>>>(hA, W4, b4, csr, rnd, dinv, hB, n);

    // ---- fused segment max pool + MLP ----
    k_poolmlp<<<N_GRAPHS, 256, 0, stream>>>(hB, gst, L1w, L1b, L2w, L2b, L3w, L3b, out);
}